// Round 10
// baseline (660.121 us; speedup 1.0000x reference)
//
#include <hip/hip_runtime.h>
#include <math.h>

#define NCH   256
#define HH    112
#define WW    112
#define NB    8
#define PLANE (HH*WW)          // 12544
#define LSTR  132              // LDS row stride in floats (row bank shift = 4)
#define LOFF  9                // interior col offset (reads at c0+4 are 16B aligned)
#define COLG  (WW/8)           // 14 column groups of 8
#define ROWS_PER 56            // output rows per block (half plane)
#define TROWS 66               // 56 + 2*5 halo
#define NTASK (ROWS_PER*COLG)  // 784 strip tasks (1x8) per half-plane
#define CTASK ((ROWS_PER/2)*COLG) // 392 tile tasks (2x8) for conv
#define BNEPS 1e-5f

// Accumulate one branch's taps for one x-row (dy) into an 8-wide strip.
template<int K, int DIL>
__device__ __forceinline__ void branch_row(float acc[8], const float* __restrict__ wc,
                                           const int dy, const float xr[20]) {
  constexpr int P = (K - 1) / 2;
  if (dy % DIL != 0) return;
  const int q = dy / DIL;
  if (q < -P || q > P) return;
  const float* wrow = wc + (q + P) * K;
  #pragma unroll
  for (int kj = 0; kj < K; ++kj) {
    const float wv = wrow[kj];               // uniform -> s_load
    const int off = 5 + (kj - P) * DIL;
    #pragma unroll
    for (int j = 0; j < 8; ++j)
      acc[j] = fmaf(wv, xr[j + off], acc[j]);
  }
}

// Stage input rows [r0-5, r0+60] of one (n,c) plane into LDS; OOB rows and halo
// columns are zero (no bounds checks needed in the compute loops).
__device__ __forceinline__ void load_half_to_lds(float* tile, const float* __restrict__ x,
                                                 int plane, int r0, int tid) {
  float4* t4 = reinterpret_cast<float4*>(tile);
  #pragma unroll 2
  for (int i = tid; i < TROWS * LSTR / 4; i += 256) t4[i] = make_float4(0.f, 0.f, 0.f, 0.f);
  __syncthreads();
  const float* xp = x + (size_t)plane * PLANE;
  for (int i = tid; i < TROWS * (WW / 4); i += 256) {
    const int tr = i / (WW / 4);
    const int c4 = (i - tr * (WW / 4)) * 4;
    const int ir = r0 - 5 + tr;
    if (ir >= 0 && ir < HH) {
      const float4 v = *reinterpret_cast<const float4*>(xp + ir * WW + c4);
      float* d = &tile[tr * LSTR + LOFF + c4];
      d[0] = v.x; d[1] = v.y; d[2] = v.z; d[3] = v.w;
    }
  }
  __syncthreads();
}

__device__ __forceinline__ void read_row20(float xr[20], const float* base) {
  const float4* lp = reinterpret_cast<const float4*>(base);
  #pragma unroll
  for (int q = 0; q < 5; ++q) {
    const float4 v = lp[q];
    xr[4 * q] = v.x; xr[4 * q + 1] = v.y; xr[4 * q + 2] = v.z; xr[4 * q + 3] = v.w;
  }
}

// ---------------- Pass 1: per-branch per-half-plane sum / sumsq ----------------
// VERBATIM round-2/round-8 k_stats: single-pass 6-branch 8-wide, (256,4) 64-reg
// cap. Measured 267 us twice (stable). Do not perturb.
extern "C" __global__ void __launch_bounds__(256, 4)
k_stats(const float* __restrict__ x,
        const float* __restrict__ w0, const float* __restrict__ w1,
        const float* __restrict__ w2, const float* __restrict__ w3,
        const float* __restrict__ w4, const float* __restrict__ w5,
        float* __restrict__ partials)
{
  __shared__ __align__(16) float tile[TROWS * LSTR];   // 34.8 KB -> 4 blocks/CU
  const int bid   = blockIdx.x;
  const int plane = bid >> 1;
  const int r0    = (bid & 1) * ROWS_PER;
  const int ch    = plane & (NCH - 1);
  const int tid   = threadIdx.x;

  load_half_to_lds(tile, x, plane, r0, tid);

  const float* wc0 = w0 + ch * 121;
  const float* wc1 = w1 + ch * 25;
  const float* wc2 = w2 + ch * 49;
  const float* wc3 = w3 + ch * 25;
  const float* wc4 = w4 + ch * 9;
  const float* wc5 = w5 + ch * 9;

  float s[6]  = {0.f, 0.f, 0.f, 0.f, 0.f, 0.f};
  float ss[6] = {0.f, 0.f, 0.f, 0.f, 0.f, 0.f};

  for (int t = tid; t < NTASK; t += 256) {
    // lane = row mapping: consecutive lanes hit banks 4 apart -> conflict-light b128
    const int rl = t % ROWS_PER;
    const int c0 = (t / ROWS_PER) * 8;
    const float* base = &tile[(rl + 5) * LSTR + c0 + 4];   // 16B aligned
    float acc[6][8];
    #pragma unroll
    for (int b = 0; b < 6; ++b) {
      #pragma unroll
      for (int j = 0; j < 8; ++j) acc[b][j] = 0.f;
    }
    #pragma unroll
    for (int dy = -5; dy <= 5; ++dy) {
      float xr[20];
      read_row20(xr, base + dy * LSTR);      // OOB rows are zeros in LDS
      branch_row<11, 1>(acc[0], wc0, dy, xr);
      branch_row< 5, 1>(acc[1], wc1, dy, xr);
      branch_row< 7, 1>(acc[2], wc2, dy, xr);
      branch_row< 5, 2>(acc[3], wc3, dy, xr);
      branch_row< 3, 3>(acc[4], wc4, dy, xr);
      branch_row< 3, 5>(acc[5], wc5, dy, xr);
    }
    #pragma unroll
    for (int b = 0; b < 6; ++b) {
      #pragma unroll
      for (int j = 0; j < 8; ++j) { const float v = acc[b][j]; s[b] += v; ss[b] += v * v; }
    }
  }

  __syncthreads();   // done reading tile; reuse it for the reduction
  #pragma unroll
  for (int b = 0; b < 6; ++b) {
    #pragma unroll
    for (int off = 32; off > 0; off >>= 1) {
      s[b]  += __shfl_xor(s[b],  off, 64);
      ss[b] += __shfl_xor(ss[b], off, 64);
    }
  }
  const int lane = tid & 63, wid = tid >> 6;
  if (lane == 0) {
    #pragma unroll
    for (int b = 0; b < 6; ++b) { tile[wid * 12 + 2 * b] = s[b]; tile[wid * 12 + 2 * b + 1] = ss[b]; }
  }
  __syncthreads();
  if (tid < 12) {
    partials[(size_t)bid * 12 + tid] =
        tile[tid] + tile[12 + tid] + tile[24 + tid] + tile[36 + tid];
  }
}

// ---------------- Pass 2: finalize stats, build merged 11x11 kernel ----------------
template<int K, int DIL>
__device__ __forceinline__ void merge_k(float* wmv, const float* __restrict__ wc, const float sc) {
  constexpr int P = (K - 1) / 2;
  #pragma unroll
  for (int ki = 0; ki < K; ++ki) {
    #pragma unroll
    for (int kj = 0; kj < K; ++kj) {
      const int idx = ((ki - P) * DIL + 5) * 11 + ((kj - P) * DIL + 5);
      wmv[idx] += sc * wc[ki * K + kj];
    }
  }
}

extern "C" __global__ void __launch_bounds__(256)
k_merge(const float* __restrict__ partials,
        const float* __restrict__ w0, const float* __restrict__ g0, const float* __restrict__ b0,
        const float* __restrict__ w1, const float* __restrict__ g1, const float* __restrict__ b1,
        const float* __restrict__ w2, const float* __restrict__ g2, const float* __restrict__ b2,
        const float* __restrict__ w3, const float* __restrict__ g3, const float* __restrict__ b3,
        const float* __restrict__ w4, const float* __restrict__ g4, const float* __restrict__ b4,
        const float* __restrict__ w5, const float* __restrict__ g5, const float* __restrict__ b5,
        float* __restrict__ wm, float* __restrict__ bias)
{
  const int ch = threadIdx.x;          // one thread per channel, single block of 256
  const float invc = 1.f / (float)(NB * PLANE);
  float wmv[121];
  #pragma unroll
  for (int i = 0; i < 121; ++i) wmv[i] = 0.f;
  float bacc = 0.f;

#define BR_STATS(B)                                                                 \
    float S = 0.f, SS = 0.f;                                                        \
    for (int n = 0; n < NB; ++n) {                                                  \
      for (int h = 0; h < 2; ++h) {                                                 \
        const float* p = &partials[(size_t)((n * NCH + ch) * 2 + h) * 12 + 2 * (B)];\
        S += p[0]; SS += p[1];                                                      \
      }                                                                             \
    }                                                                               \
    const float m = S * invc;                                                       \
    const float v = fmaxf(SS * invc - m * m, 0.f);

  { BR_STATS(0) const float sc = g0[ch] / sqrtf(v + BNEPS); bacc += b0[ch] - m * sc; merge_k<11, 1>(wmv, w0 + ch * 121, sc); }
  { BR_STATS(1) const float sc = g1[ch] / sqrtf(v + BNEPS); bacc += b1[ch] - m * sc; merge_k< 5, 1>(wmv, w1 + ch * 25,  sc); }
  { BR_STATS(2) const float sc = g2[ch] / sqrtf(v + BNEPS); bacc += b2[ch] - m * sc; merge_k< 7, 1>(wmv, w2 + ch * 49,  sc); }
  { BR_STATS(3) const float sc = g3[ch] / sqrtf(v + BNEPS); bacc += b3[ch] - m * sc; merge_k< 5, 2>(wmv, w3 + ch * 25,  sc); }
  { BR_STATS(4) const float sc = g4[ch] / sqrtf(v + BNEPS); bacc += b4[ch] - m * sc; merge_k< 3, 3>(wmv, w4 + ch * 9,   sc); }
  { BR_STATS(5) const float sc = g5[ch] / sqrtf(v + BNEPS); bacc += b5[ch] - m * sc; merge_k< 3, 5>(wmv, w5 + ch * 9,   sc); }
#undef BR_STATS

  #pragma unroll
  for (int i = 0; i < 121; ++i) wm[(size_t)ch * 121 + i] = wmv[i];
  bias[ch] = bacc;
}

// ---------------- Pass 3: merged 11x11 conv, 2x8 register tiles ----------------
// r3's conv VERBATIM except ONE change: weights read from an LDS copy (wsh)
// instead of global (wmc). Global-uniform weight reads compile to s_load, and
// SMEM shares lgkmcnt with ds_read but returns out-of-order -> every weight
// use forces lgkmcnt(0), draining the x-tile ds_read pipeline once per kernel
// row. ds_read weights are in-order -> counted waits, pipelining preserved.
// Same live values as r3 (no rolling regs - that was r9's spill cause).
extern "C" __global__ void __launch_bounds__(256, 4)
k_conv(const float* __restrict__ x, const float* __restrict__ wm,
       const float* __restrict__ bias, float* __restrict__ out)
{
  __shared__ __align__(16) float tile[TROWS * LSTR];
  __shared__ __align__(16) float wsh[121];
  const int bid   = blockIdx.x;
  const int plane = bid >> 1;
  const int r0    = (bid & 1) * ROWS_PER;
  const int ch    = plane & (NCH - 1);
  const int tid   = threadIdx.x;

  if (tid < 121) wsh[tid] = wm[(size_t)ch * 121 + tid];
  load_half_to_lds(tile, x, plane, r0, tid);   // barriers inside make wsh visible

  const float* wmc = wsh;                      // the single diff vs r3
  const float bc   = bias[ch];
  float* op = out + (size_t)plane * PLANE;

  for (int t = tid; t < CTASK; t += 256) {
    // cg fastest: coalesced global stores
    const int rg = t / COLG;                 // 0..27 (row pair)
    const int c0 = (t - rg * COLG) * 8;
    const float* base = &tile[(2 * rg) * LSTR + c0 + 4];   // tr = 2rg + d
    float a0[8], a1[8];
    #pragma unroll
    for (int j = 0; j < 8; ++j) { a0[j] = bc; a1[j] = bc; }

    // 12 shared input rows feed both output rows (weight rows d and d-1)
    #pragma unroll
    for (int d = 0; d < 12; ++d) {
      float xr[20];
      read_row20(xr, base + d * LSTR);
      if (d < 11) {
        const float* wr = wmc + d * 11;
        #pragma unroll
        for (int kj = 0; kj < 11; ++kj) {
          const float wv = wr[kj];
          #pragma unroll
          for (int j = 0; j < 8; ++j) a0[j] = fmaf(wv, xr[j + kj], a0[j]);
        }
      }
      if (d >= 1) {
        const float* wr = wmc + (d - 1) * 11;
        #pragma unroll
        for (int kj = 0; kj < 11; ++kj) {
          const float wv = wr[kj];
          #pragma unroll
          for (int j = 0; j < 8; ++j) a1[j] = fmaf(wv, xr[j + kj], a1[j]);
        }
      }
    }
    float* dst0 = &op[(r0 + 2 * rg) * WW + c0];
    float* dst1 = dst0 + WW;
    reinterpret_cast<float4*>(dst0)[0] = make_float4(a0[0], a0[1], a0[2], a0[3]);
    reinterpret_cast<float4*>(dst0)[1] = make_float4(a0[4], a0[5], a0[6], a0[7]);
    reinterpret_cast<float4*>(dst1)[0] = make_float4(a1[0], a1[1], a1[2], a1[3]);
    reinterpret_cast<float4*>(dst1)[1] = make_float4(a1[4], a1[5], a1[6], a1[7]);
  }
}

extern "C" void kernel_launch(void* const* d_in, const int* in_sizes, int n_in,
                              void* d_out, int out_size, void* d_ws, size_t ws_size,
                              hipStream_t stream) {
  (void)in_sizes; (void)n_in; (void)out_size; (void)ws_size;
  const float* x   = (const float*)d_in[0];
  const float* w0  = (const float*)d_in[1];
  const float* g0  = (const float*)d_in[2];
  const float* b0  = (const float*)d_in[3];
  const float* w1  = (const float*)d_in[4];
  const float* g1  = (const float*)d_in[5];
  const float* b1  = (const float*)d_in[6];
  const float* w2  = (const float*)d_in[7];
  const float* g2  = (const float*)d_in[8];
  const float* b2  = (const float*)d_in[9];
  const float* w3  = (const float*)d_in[10];
  const float* g3  = (const float*)d_in[11];
  const float* b3  = (const float*)d_in[12];
  const float* w4  = (const float*)d_in[13];
  const float* g4  = (const float*)d_in[14];
  const float* b4  = (const float*)d_in[15];
  const float* w5  = (const float*)d_in[16];
  const float* g5  = (const float*)d_in[17];
  const float* b5  = (const float*)d_in[18];

  float* partials = (float*)d_ws;                    // 4096*12 floats
  float* wm       = partials + 4096 * 12;            // 256*121 floats
  float* bias     = wm + 256 * 121;                  // 256 floats
  float* outp     = (float*)d_out;

  k_stats<<<dim3(NB * NCH * 2), dim3(256), 0, stream>>>(x, w0, w1, w2, w3, w4, w5, partials);
  k_merge<<<dim3(1), dim3(256), 0, stream>>>(partials,
      w0, g0, b0, w1, g1, b1, w2, g2, b2, w3, g3, b3, w4, g4, b4, w5, g5, b5,
      wm, bias);
  k_conv<<<dim3(NB * NCH * 2), dim3(256), 0, stream>>>(x, wm, bias, outp);
}

// Round 11
// 405.762 us; speedup vs baseline: 1.6269x; 1.6269x over previous
//
#include <hip/hip_runtime.h>
#include <math.h>

#define NCH   256
#define HH    112
#define WW    112
#define NB    8
#define PLANE (HH*WW)          // 12544
#define LSTR  132              // LDS row stride in floats (row bank shift = 4)
#define LOFF  9                // interior col offset (reads at c0+4 are 16B aligned)
#define COLG  (WW/8)           // 14 column groups of 8
#define ROWS_PER 56            // output rows per block (half plane)
#define TROWS 66               // 56 + 2*5 halo
#define NTASK (ROWS_PER*COLG)  // 784 strip tasks (1x8) per half-plane
#define CTASK ((ROWS_PER/2)*COLG) // 392 tile tasks (2x8) for conv
#define BNEPS 1e-5f

// Accumulate one branch's taps for one x-row (dy) into an 8-wide strip.
template<int K, int DIL>
__device__ __forceinline__ void branch_row(float acc[8], const float* __restrict__ wc,
                                           const int dy, const float xr[20]) {
  constexpr int P = (K - 1) / 2;
  if (dy % DIL != 0) return;
  const int q = dy / DIL;
  if (q < -P || q > P) return;
  const float* wrow = wc + (q + P) * K;
  #pragma unroll
  for (int kj = 0; kj < K; ++kj) {
    const float wv = wrow[kj];               // uniform -> s_load (SGPR-resident: keeps VGPRs at 64)
    const int off = 5 + (kj - P) * DIL;
    #pragma unroll
    for (int j = 0; j < 8; ++j)
      acc[j] = fmaf(wv, xr[j + off], acc[j]);
  }
}

// Stage input rows [r0-5, r0+60] of one (n,c) plane into LDS; OOB rows and halo
// columns are zero (no bounds checks needed in the compute loops).
__device__ __forceinline__ void load_half_to_lds(float* tile, const float* __restrict__ x,
                                                 int plane, int r0, int tid) {
  float4* t4 = reinterpret_cast<float4*>(tile);
  #pragma unroll 2
  for (int i = tid; i < TROWS * LSTR / 4; i += 256) t4[i] = make_float4(0.f, 0.f, 0.f, 0.f);
  __syncthreads();
  const float* xp = x + (size_t)plane * PLANE;
  for (int i = tid; i < TROWS * (WW / 4); i += 256) {
    const int tr = i / (WW / 4);
    const int c4 = (i - tr * (WW / 4)) * 4;
    const int ir = r0 - 5 + tr;
    if (ir >= 0 && ir < HH) {
      const float4 v = *reinterpret_cast<const float4*>(xp + ir * WW + c4);
      float* d = &tile[tr * LSTR + LOFF + c4];
      d[0] = v.x; d[1] = v.y; d[2] = v.z; d[3] = v.w;
    }
  }
  __syncthreads();
}

__device__ __forceinline__ void read_row20(float xr[20], const float* base) {
  const float4* lp = reinterpret_cast<const float4*>(base);
  #pragma unroll
  for (int q = 0; q < 5; ++q) {
    const float4 v = lp[q];
    xr[4 * q] = v.x; xr[4 * q + 1] = v.y; xr[4 * q + 2] = v.z; xr[4 * q + 3] = v.w;
  }
}

// ---------------- Pass 1: per-branch per-half-plane sum / sumsq ----------------
// VERBATIM round-2/round-8 k_stats: single-pass 6-branch 8-wide, (256,4) 64-reg
// cap. Measured 267 us three times (stable). Do not perturb: spill behavior
// under the compiler's weight-hoist heuristic is knife-edge (r6/r7/r9/r10:
// 0.5-4.5 GB scratch traffic from "equivalent" variants).
extern "C" __global__ void __launch_bounds__(256, 4)
k_stats(const float* __restrict__ x,
        const float* __restrict__ w0, const float* __restrict__ w1,
        const float* __restrict__ w2, const float* __restrict__ w3,
        const float* __restrict__ w4, const float* __restrict__ w5,
        float* __restrict__ partials)
{
  __shared__ __align__(16) float tile[TROWS * LSTR];   // 34.8 KB -> 4 blocks/CU
  const int bid   = blockIdx.x;
  const int plane = bid >> 1;
  const int r0    = (bid & 1) * ROWS_PER;
  const int ch    = plane & (NCH - 1);
  const int tid   = threadIdx.x;

  load_half_to_lds(tile, x, plane, r0, tid);

  const float* wc0 = w0 + ch * 121;
  const float* wc1 = w1 + ch * 25;
  const float* wc2 = w2 + ch * 49;
  const float* wc3 = w3 + ch * 25;
  const float* wc4 = w4 + ch * 9;
  const float* wc5 = w5 + ch * 9;

  float s[6]  = {0.f, 0.f, 0.f, 0.f, 0.f, 0.f};
  float ss[6] = {0.f, 0.f, 0.f, 0.f, 0.f, 0.f};

  for (int t = tid; t < NTASK; t += 256) {
    // lane = row mapping: consecutive lanes hit banks 4 apart -> conflict-light b128
    const int rl = t % ROWS_PER;
    const int c0 = (t / ROWS_PER) * 8;
    const float* base = &tile[(rl + 5) * LSTR + c0 + 4];   // 16B aligned
    float acc[6][8];
    #pragma unroll
    for (int b = 0; b < 6; ++b) {
      #pragma unroll
      for (int j = 0; j < 8; ++j) acc[b][j] = 0.f;
    }
    #pragma unroll
    for (int dy = -5; dy <= 5; ++dy) {
      float xr[20];
      read_row20(xr, base + dy * LSTR);      // OOB rows are zeros in LDS
      branch_row<11, 1>(acc[0], wc0, dy, xr);
      branch_row< 5, 1>(acc[1], wc1, dy, xr);
      branch_row< 7, 1>(acc[2], wc2, dy, xr);
      branch_row< 5, 2>(acc[3], wc3, dy, xr);
      branch_row< 3, 3>(acc[4], wc4, dy, xr);
      branch_row< 3, 5>(acc[5], wc5, dy, xr);
    }
    #pragma unroll
    for (int b = 0; b < 6; ++b) {
      #pragma unroll
      for (int j = 0; j < 8; ++j) { const float v = acc[b][j]; s[b] += v; ss[b] += v * v; }
    }
  }

  __syncthreads();   // done reading tile; reuse it for the reduction
  #pragma unroll
  for (int b = 0; b < 6; ++b) {
    #pragma unroll
    for (int off = 32; off > 0; off >>= 1) {
      s[b]  += __shfl_xor(s[b],  off, 64);
      ss[b] += __shfl_xor(ss[b], off, 64);
    }
  }
  const int lane = tid & 63, wid = tid >> 6;
  if (lane == 0) {
    #pragma unroll
    for (int b = 0; b < 6; ++b) { tile[wid * 12 + 2 * b] = s[b]; tile[wid * 12 + 2 * b + 1] = ss[b]; }
  }
  __syncthreads();
  if (tid < 12) {
    partials[(size_t)bid * 12 + tid] =
        tile[tid] + tile[12 + tid] + tile[24 + tid] + tile[36 + tid];
  }
}

// ---------------- Pass 2: finalize stats, build merged 11x11 kernel ----------------
// Only change vs r8: distributed across 4 blocks x 64 threads (was 1x256) to
// shrink the whole-GPU serialization bubble between k_stats and k_conv.
template<int K, int DIL>
__device__ __forceinline__ void merge_k(float* wmv, const float* __restrict__ wc, const float sc) {
  constexpr int P = (K - 1) / 2;
  #pragma unroll
  for (int ki = 0; ki < K; ++ki) {
    #pragma unroll
    for (int kj = 0; kj < K; ++kj) {
      const int idx = ((ki - P) * DIL + 5) * 11 + ((kj - P) * DIL + 5);
      wmv[idx] += sc * wc[ki * K + kj];
    }
  }
}

extern "C" __global__ void __launch_bounds__(64)
k_merge(const float* __restrict__ partials,
        const float* __restrict__ w0, const float* __restrict__ g0, const float* __restrict__ b0,
        const float* __restrict__ w1, const float* __restrict__ g1, const float* __restrict__ b1,
        const float* __restrict__ w2, const float* __restrict__ g2, const float* __restrict__ b2,
        const float* __restrict__ w3, const float* __restrict__ g3, const float* __restrict__ b3,
        const float* __restrict__ w4, const float* __restrict__ g4, const float* __restrict__ b4,
        const float* __restrict__ w5, const float* __restrict__ g5, const float* __restrict__ b5,
        float* __restrict__ wm, float* __restrict__ bias)
{
  const int ch = blockIdx.x * 64 + threadIdx.x;   // one thread per channel, 4 blocks
  const float invc = 1.f / (float)(NB * PLANE);
  float wmv[121];
  #pragma unroll
  for (int i = 0; i < 121; ++i) wmv[i] = 0.f;
  float bacc = 0.f;

#define BR_STATS(B)                                                                 \
    float S = 0.f, SS = 0.f;                                                        \
    for (int n = 0; n < NB; ++n) {                                                  \
      for (int h = 0; h < 2; ++h) {                                                 \
        const float* p = &partials[(size_t)((n * NCH + ch) * 2 + h) * 12 + 2 * (B)];\
        S += p[0]; SS += p[1];                                                      \
      }                                                                             \
    }                                                                               \
    const float m = S * invc;                                                       \
    const float v = fmaxf(SS * invc - m * m, 0.f);

  { BR_STATS(0) const float sc = g0[ch] / sqrtf(v + BNEPS); bacc += b0[ch] - m * sc; merge_k<11, 1>(wmv, w0 + ch * 121, sc); }
  { BR_STATS(1) const float sc = g1[ch] / sqrtf(v + BNEPS); bacc += b1[ch] - m * sc; merge_k< 5, 1>(wmv, w1 + ch * 25,  sc); }
  { BR_STATS(2) const float sc = g2[ch] / sqrtf(v + BNEPS); bacc += b2[ch] - m * sc; merge_k< 7, 1>(wmv, w2 + ch * 49,  sc); }
  { BR_STATS(3) const float sc = g3[ch] / sqrtf(v + BNEPS); bacc += b3[ch] - m * sc; merge_k< 5, 2>(wmv, w3 + ch * 25,  sc); }
  { BR_STATS(4) const float sc = g4[ch] / sqrtf(v + BNEPS); bacc += b4[ch] - m * sc; merge_k< 3, 3>(wmv, w4 + ch * 9,   sc); }
  { BR_STATS(5) const float sc = g5[ch] / sqrtf(v + BNEPS); bacc += b5[ch] - m * sc; merge_k< 3, 5>(wmv, w5 + ch * 9,   sc); }
#undef BR_STATS

  #pragma unroll
  for (int i = 0; i < 121; ++i) wm[(size_t)ch * 121 + i] = wmv[i];
  bias[ch] = bacc;
}

// ---------------- Pass 3: merged 11x11 conv, 2x8 register tiles ----------------
// VERBATIM round-3/round-8 k_conv: weights from global (s_load -> SGPR; any
// VGPR-resident weight scheme crosses the 64-reg spill cliff, r9/r10).
extern "C" __global__ void __launch_bounds__(256, 4)
k_conv(const float* __restrict__ x, const float* __restrict__ wm,
       const float* __restrict__ bias, float* __restrict__ out)
{
  __shared__ __align__(16) float tile[TROWS * LSTR];
  const int bid   = blockIdx.x;
  const int plane = bid >> 1;
  const int r0    = (bid & 1) * ROWS_PER;
  const int ch    = plane & (NCH - 1);
  const int tid   = threadIdx.x;

  load_half_to_lds(tile, x, plane, r0, tid);

  const float* wmc = wm + (size_t)ch * 121;
  const float bc   = bias[ch];
  float* op = out + (size_t)plane * PLANE;

  for (int t = tid; t < CTASK; t += 256) {
    // cg fastest: coalesced global stores
    const int rg = t / COLG;                 // 0..27 (row pair)
    const int c0 = (t - rg * COLG) * 8;
    const float* base = &tile[(2 * rg) * LSTR + c0 + 4];   // tr = 2rg + d
    float a0[8], a1[8];
    #pragma unroll
    for (int j = 0; j < 8; ++j) { a0[j] = bc; a1[j] = bc; }

    // 12 shared input rows feed both output rows (weight rows d and d-1)
    #pragma unroll
    for (int d = 0; d < 12; ++d) {
      float xr[20];
      read_row20(xr, base + d * LSTR);
      if (d < 11) {
        const float* wr = wmc + d * 11;
        #pragma unroll
        for (int kj = 0; kj < 11; ++kj) {
          const float wv = wr[kj];
          #pragma unroll
          for (int j = 0; j < 8; ++j) a0[j] = fmaf(wv, xr[j + kj], a0[j]);
        }
      }
      if (d >= 1) {
        const float* wr = wmc + (d - 1) * 11;
        #pragma unroll
        for (int kj = 0; kj < 11; ++kj) {
          const float wv = wr[kj];
          #pragma unroll
          for (int j = 0; j < 8; ++j) a1[j] = fmaf(wv, xr[j + kj], a1[j]);
        }
      }
    }
    float* dst0 = &op[(r0 + 2 * rg) * WW + c0];
    float* dst1 = dst0 + WW;
    reinterpret_cast<float4*>(dst0)[0] = make_float4(a0[0], a0[1], a0[2], a0[3]);
    reinterpret_cast<float4*>(dst0)[1] = make_float4(a0[4], a0[5], a0[6], a0[7]);
    reinterpret_cast<float4*>(dst1)[0] = make_float4(a1[0], a1[1], a1[2], a1[3]);
    reinterpret_cast<float4*>(dst1)[1] = make_float4(a1[4], a1[5], a1[6], a1[7]);
  }
}

extern "C" void kernel_launch(void* const* d_in, const int* in_sizes, int n_in,
                              void* d_out, int out_size, void* d_ws, size_t ws_size,
                              hipStream_t stream) {
  (void)in_sizes; (void)n_in; (void)out_size; (void)ws_size;
  const float* x   = (const float*)d_in[0];
  const float* w0  = (const float*)d_in[1];
  const float* g0  = (const float*)d_in[2];
  const float* b0  = (const float*)d_in[3];
  const float* w1  = (const float*)d_in[4];
  const float* g1  = (const float*)d_in[5];
  const float* b1  = (const float*)d_in[6];
  const float* w2  = (const float*)d_in[7];
  const float* g2  = (const float*)d_in[8];
  const float* b2  = (const float*)d_in[9];
  const float* w3  = (const float*)d_in[10];
  const float* g3  = (const float*)d_in[11];
  const float* b3  = (const float*)d_in[12];
  const float* w4  = (const float*)d_in[13];
  const float* g4  = (const float*)d_in[14];
  const float* b4  = (const float*)d_in[15];
  const float* w5  = (const float*)d_in[16];
  const float* g5  = (const float*)d_in[17];
  const float* b5  = (const float*)d_in[18];

  float* partials = (float*)d_ws;                    // 4096*12 floats
  float* wm       = partials + 4096 * 12;            // 256*121 floats
  float* bias     = wm + 256 * 121;                  // 256 floats
  float* outp     = (float*)d_out;

  k_stats<<<dim3(NB * NCH * 2), dim3(256), 0, stream>>>(x, w0, w1, w2, w3, w4, w5, partials);
  k_merge<<<dim3(4), dim3(64), 0, stream>>>(partials,
      w0, g0, b0, w1, g1, b1, w2, g2, b2, w3, g3, b3, w4, g4, b4, w5, g5, b5,
      wm, bias);
  k_conv<<<dim3(NB * NCH * 2), dim3(256), 0, stream>>>(x, wm, bias, outp);
}